// Round 6
// baseline (388.537 us; speedup 1.0000x reference)
//
#include <hip/hip_runtime.h>

#define NBATCH 8
#define NPB 4096                  // points per batch per cloud
#define BLK 512                   // 8 waves
#define ONEBF 0x3F80u
#define SCALE2 (2.0f / 32768.0f)  // dist = 2*S, mean over B*N per direction

typedef short short8 __attribute__((ext_vector_type(8)));
typedef float f32x16 __attribute__((ext_vector_type(16)));

__device__ __forceinline__ unsigned short bf16rn(float x) {
  unsigned int u = __float_as_uint(x);
  unsigned int r = (u + 0x7fffu + ((u >> 16) & 1u)) >> 16;
  return (unsigned short)r;
}
__device__ __forceinline__ float bf16tof(unsigned short h) {
  return __uint_as_float(((unsigned int)h) << 16);
}
__device__ __forceinline__ uint4 pack8(unsigned short s0, unsigned short s1,
                                       unsigned short s2, unsigned short s3,
                                       unsigned short s4, unsigned short s5,
                                       unsigned short s6, unsigned short s7) {
  uint4 r;
  r.x = (unsigned)s0 | ((unsigned)s1 << 16);
  r.y = (unsigned)s2 | ((unsigned)s3 << 16);
  r.z = (unsigned)s4 | ((unsigned)s5 << 16);
  r.w = (unsigned)s6 | ((unsigned)s7 << 16);
  return r;
}
__device__ __forceinline__ float m3(float a, float b, float c) {
  return fminf(fminf(a, b), c);   // v_min3_f32 bait
}
__device__ __forceinline__ float fold16(f32x16 a) {
  float p0 = m3(a[0], a[1], a[2]);
  float p1 = m3(a[3], a[4], a[5]);
  float p2 = m3(a[6], a[7], a[8]);
  float p3 = m3(a[9], a[10], a[11]);
  float p4 = m3(a[12], a[13], a[14]);
  float q0 = m3(p0, p1, a[15]);
  float q1 = m3(p2, p3, p4);
  return fminf(q0, q1);
}

// ------------- single fused kernel ------------------------------------------
// S[n,m] = (|p|^2+|t|^2)/2 - p.t  via 13 bf16-split K-slots (verified r3-r5):
// A half0: [hx,hy,hz, lx,ly,lz, hx,hy]   A half1: [hz, nh, nl, 1, 1, 0,0,0]
// B half0: [-hx,-hy,-hz,-hx,-hy,-hz,-lx,-ly]  B half1: [-lz, 1, 1, nh, nl, 0,0,0]
// grid = [d(2)][b(8)][cg(16)] = 256 blocks x 8 waves (1 block/CU, 2 waves/SIMD).
// wave w: rows w*512..+511 (A from LDS, 8 steps of 64), ALL 256 cols
// (8 B-frags from LDS once, acc[8] col-min in registers). Row split across
// waves halves DS traffic vs col split. atomicAdd block partial into out.
__global__ __launch_bounds__(BLK, 2)
void chamfer_fused_kernel(const float* __restrict__ pred,
                          const float* __restrict__ tgt,
                          float* __restrict__ out) {
  __shared__ unsigned char afr[2][NPB][16];   // 128 KB: [half][row][16B]
  __shared__ unsigned char bfr[2][256][16];   // 8 KB: [half][col][16B]
  __shared__ float cmin[8][256];              // 8 KB
  __shared__ float ssum[8];

  int bid = (int)blockIdx.x;
  int cg = bid & 15;
  int b  = (bid >> 4) & 7;
  int d  = bid >> 7;
  int tid = (int)threadIdx.x;
  int w    = tid >> 6;
  int lane = tid & 63;
  int l31  = lane & 31;
  int half = lane >> 5;

  // dir 0: per-PRED-point min over TARGET -> rows = target, cols = pred
  const float* Ac = (d == 0 ? tgt : pred) + (size_t)b * NPB * 3;
  const float* Bc = (d == 0 ? pred : tgt) + (size_t)b * NPB * 3;

  // ---- phase 1a: A-frags for all 4096 rows -> LDS (512 thr x 8 rows) ----
  #pragma unroll 4
  for (int k = 0; k < 8; ++k) {
    int r = tid + k * BLK;
    float x = Ac[3 * r + 0], y = Ac[3 * r + 1], z = Ac[3 * r + 2];
    unsigned short hx = bf16rn(x), hy = bf16rn(y), hz = bf16rn(z);
    unsigned short lx = bf16rn(x - bf16tof(hx));
    unsigned short ly = bf16rn(y - bf16tof(hy));
    unsigned short lz = bf16rn(z - bf16tof(hz));
    float nq = 0.5f * (x * x + y * y + z * z);
    unsigned short nh = bf16rn(nq);
    unsigned short nl = bf16rn(nq - bf16tof(nh));
    *(uint4*)&afr[0][r][0] = pack8(hx, hy, hz, lx, ly, lz, hx, hy);
    *(uint4*)&afr[1][r][0] = pack8(hz, nh, nl, ONEBF, ONEBF, 0, 0, 0);
  }

  // ---- phase 1b: B-frags for this block's 256 cols -> LDS (once) ----
  if (tid < 256) {
    int col = cg * 256 + tid;
    float x = Bc[3 * col + 0], y = Bc[3 * col + 1], z = Bc[3 * col + 2];
    unsigned short hx = bf16rn(x), hy = bf16rn(y), hz = bf16rn(z);
    unsigned short lx = bf16rn(x - bf16tof(hx));
    unsigned short ly = bf16rn(y - bf16tof(hy));
    unsigned short lz = bf16rn(z - bf16tof(hz));
    float nq = 0.5f * (x * x + y * y + z * z);
    unsigned short nh = bf16rn(nq);
    unsigned short nl = bf16rn(nq - bf16tof(nh));
    unsigned short mhx = hx ^ 0x8000u, mhy = hy ^ 0x8000u, mhz = hz ^ 0x8000u;
    unsigned short mlx = lx ^ 0x8000u, mly = ly ^ 0x8000u, mlz = lz ^ 0x8000u;
    *(uint4*)&bfr[0][tid][0] = pack8(mhx, mhy, mhz, mhx, mhy, mhz, mlx, mly);
    *(uint4*)&bfr[1][tid][0] = pack8(mlz, ONEBF, ONEBF, nh, nl, 0, 0, 0);
  }

  __syncthreads();

  // ---- phase 2: load 8 B-frags, run 8 row-steps over this wave's 512 rows ---
  short8 bf[8];
  #pragma unroll
  for (int j = 0; j < 8; ++j)
    bf[j] = *(const short8*)&bfr[half][j * 32 + l31][0];

  f32x16 acc[8];
  #pragma unroll
  for (int j = 0; j < 8; ++j)
    #pragma unroll
    for (int i = 0; i < 16; ++i) acc[j][i] = 1e30f;

  f32x16 zero = {};
  const unsigned char* abase = &afr[half][w * 512][0];

  #pragma unroll
  for (int step = 0; step < 8; ++step) {
    const unsigned char* a = abase + (size_t)step * (64 * 16) + (size_t)l31 * 16;
    short8 af0 = *(const short8*)(a);
    short8 af1 = *(const short8*)(a + 32 * 16);
    #pragma unroll
    for (int j = 0; j < 8; ++j) {
      f32x16 c0 = __builtin_amdgcn_mfma_f32_32x32x16_bf16(af0, bf[j], zero, 0, 0, 0);
      f32x16 c1 = __builtin_amdgcn_mfma_f32_32x32x16_bf16(af1, bf[j], zero, 0, 0, 0);
      #pragma unroll
      for (int i = 0; i < 16; ++i) acc[j][i] = m3(acc[j][i], c0[i], c1[i]);
    }
  }

  // ---- tail: fold rows, combine row-parity halves, cross-wave col min ----
  #pragma unroll
  for (int j = 0; j < 8; ++j) {
    float m = fold16(acc[j]);
    m = fminf(m, __shfl_xor(m, 32, 64));
    if (half == 0) cmin[w][j * 32 + l31] = m;
  }
  __syncthreads();

  float v = 0.f;
  if (tid < 256) {
    float m0 = fminf(cmin[0][tid], cmin[1][tid]);
    float m1 = fminf(cmin[2][tid], cmin[3][tid]);
    float m2 = fminf(cmin[4][tid], cmin[5][tid]);
    float m3v = fminf(cmin[6][tid], cmin[7][tid]);
    v = fmaxf(fminf(fminf(m0, m1), fminf(m2, m3v)), 0.0f);
  }
  // block sum (512 threads, threads >=256 contribute 0)
  #pragma unroll
  for (int off = 32; off > 0; off >>= 1)
    v += __shfl_down(v, off, 64);
  if (lane == 0) ssum[w] = v;
  __syncthreads();
  if (tid == 0) {
    float s = 0.f;
    #pragma unroll
    for (int q = 0; q < 8; ++q) s += ssum[q];
    atomicAdd(out, s * SCALE2);
  }
}

extern "C" void kernel_launch(void* const* d_in, const int* in_sizes, int n_in,
                              void* d_out, int out_size, void* d_ws, size_t ws_size,
                              hipStream_t stream) {
  const float* pred = (const float*)d_in[0];
  const float* tgt  = (const float*)d_in[1];
  float* out = (float*)d_out;
  (void)d_ws; (void)ws_size;

  hipMemsetAsync(out, 0, sizeof(float), stream);
  chamfer_fused_kernel<<<256, BLK, 0, stream>>>(pred, tgt, out);
}

// Round 7
// 22.070 us; speedup vs baseline: 17.6049x; 17.6049x over previous
//
#include <hip/hip_runtime.h>

#define NBATCH 8
#define NPB 4096                  // points per batch per cloud
#define BLK 512                   // 8 waves
#define ONEBF 0x3F80u
#define SCALE2 (2.0f / 32768.0f)  // dist = 2*S, mean over B*N per direction

typedef short short8 __attribute__((ext_vector_type(8)));
typedef float f32x16 __attribute__((ext_vector_type(16)));

__device__ __forceinline__ unsigned short bf16rn(float x) {
  unsigned int u = __float_as_uint(x);
  unsigned int r = (u + 0x7fffu + ((u >> 16) & 1u)) >> 16;
  return (unsigned short)r;
}
__device__ __forceinline__ float bf16tof(unsigned short h) {
  return __uint_as_float(((unsigned int)h) << 16);
}
__device__ __forceinline__ uint4 pack8(unsigned short s0, unsigned short s1,
                                       unsigned short s2, unsigned short s3,
                                       unsigned short s4, unsigned short s5,
                                       unsigned short s6, unsigned short s7) {
  uint4 r;
  r.x = (unsigned)s0 | ((unsigned)s1 << 16);
  r.y = (unsigned)s2 | ((unsigned)s3 << 16);
  r.z = (unsigned)s4 | ((unsigned)s5 << 16);
  r.w = (unsigned)s6 | ((unsigned)s7 << 16);
  return r;
}
__device__ __forceinline__ float m3(float a, float b, float c) {
  return fminf(fminf(a, b), c);   // v_min3_f32 bait
}
__device__ __forceinline__ float fold16(f32x16 a) {
  float p0 = m3(a[0], a[1], a[2]);
  float p1 = m3(a[3], a[4], a[5]);
  float p2 = m3(a[6], a[7], a[8]);
  float p3 = m3(a[9], a[10], a[11]);
  float p4 = m3(a[12], a[13], a[14]);
  float q0 = m3(p0, p1, a[15]);
  float q1 = m3(p2, p3, p4);
  return fminf(q0, q1);
}

// ------------- single fused kernel ------------------------------------------
// S[n,m] = (|p|^2+|t|^2)/2 - p.t  via 13 bf16-split K-slots (verified r3-r5):
// A half0: [hx,hy,hz, lx,ly,lz, hx,hy]   A half1: [hz, nh, nl, 1, 1, 0,0,0]
// B half0: [-hx,-hy,-hz,-hx,-hy,-hz,-lx,-ly]  B half1: [-lz, 1, 1, nh, nl, 0,0,0]
// grid = [d(2)][b(8)][cg(16)] = 256 blocks x 8 waves (1 block/CU, 2 waves/SIMD).
// wave w: col half cw=w&1 (128 cols, 4 B-frags, acc[4]=64 VGPR), row quarter
// rq=w>>1 (1024 rows, 16 steps of 64). Register budget ~160 VGPR -> NO SPILL
// (round 6 lesson: acc[8] = 128 VGPR alone blew the 2-wave budget -> scratch).
__global__ __launch_bounds__(BLK, 2)
void chamfer_fused_kernel(const float* __restrict__ pred,
                          const float* __restrict__ tgt,
                          float* __restrict__ out) {
  __shared__ unsigned char afr[2][NPB][16];   // 128 KB: [half][row][16B]
  __shared__ unsigned char bfr[2][256][16];   // 8 KB: [half][col][16B]
  __shared__ float cmin[8][128];              // 4 KB
  __shared__ float ssum[8];

  int bid = (int)blockIdx.x;
  int cg = bid & 15;
  int b  = (bid >> 4) & 7;
  int d  = bid >> 7;
  int tid = (int)threadIdx.x;
  int w    = tid >> 6;
  int lane = tid & 63;
  int l31  = lane & 31;
  int half = lane >> 5;
  int cw = w & 1;       // col half (128 cols)
  int rq = w >> 1;      // row quarter (1024 rows)

  // dir 0: per-PRED-point min over TARGET -> rows = target, cols = pred
  const float* Ac = (d == 0 ? tgt : pred) + (size_t)b * NPB * 3;
  const float* Bc = (d == 0 ? pred : tgt) + (size_t)b * NPB * 3;

  // ---- phase 1a: A-frags for all 4096 rows -> LDS (512 thr x 8 rows) ----
  #pragma unroll 4
  for (int k = 0; k < 8; ++k) {
    int r = tid + k * BLK;
    float x = Ac[3 * r + 0], y = Ac[3 * r + 1], z = Ac[3 * r + 2];
    unsigned short hx = bf16rn(x), hy = bf16rn(y), hz = bf16rn(z);
    unsigned short lx = bf16rn(x - bf16tof(hx));
    unsigned short ly = bf16rn(y - bf16tof(hy));
    unsigned short lz = bf16rn(z - bf16tof(hz));
    float nq = 0.5f * (x * x + y * y + z * z);
    unsigned short nh = bf16rn(nq);
    unsigned short nl = bf16rn(nq - bf16tof(nh));
    *(uint4*)&afr[0][r][0] = pack8(hx, hy, hz, lx, ly, lz, hx, hy);
    *(uint4*)&afr[1][r][0] = pack8(hz, nh, nl, ONEBF, ONEBF, 0, 0, 0);
  }

  // ---- phase 1b: B-frags for this block's 256 cols -> LDS (once) ----
  if (tid < 256) {
    int col = cg * 256 + tid;
    float x = Bc[3 * col + 0], y = Bc[3 * col + 1], z = Bc[3 * col + 2];
    unsigned short hx = bf16rn(x), hy = bf16rn(y), hz = bf16rn(z);
    unsigned short lx = bf16rn(x - bf16tof(hx));
    unsigned short ly = bf16rn(y - bf16tof(hy));
    unsigned short lz = bf16rn(z - bf16tof(hz));
    float nq = 0.5f * (x * x + y * y + z * z);
    unsigned short nh = bf16rn(nq);
    unsigned short nl = bf16rn(nq - bf16tof(nh));
    unsigned short mhx = hx ^ 0x8000u, mhy = hy ^ 0x8000u, mhz = hz ^ 0x8000u;
    unsigned short mlx = lx ^ 0x8000u, mly = ly ^ 0x8000u, mlz = lz ^ 0x8000u;
    *(uint4*)&bfr[0][tid][0] = pack8(mhx, mhy, mhz, mhx, mhy, mhz, mlx, mly);
    *(uint4*)&bfr[1][tid][0] = pack8(mlz, ONEBF, ONEBF, nh, nl, 0, 0, 0);
  }

  __syncthreads();

  // ---- phase 2: 4 B-frags in regs, 16 row-steps over this wave's 1024 rows --
  short8 bf[4];
  #pragma unroll
  for (int j = 0; j < 4; ++j)
    bf[j] = *(const short8*)&bfr[half][cw * 128 + j * 32 + l31][0];

  f32x16 acc[4];
  #pragma unroll
  for (int j = 0; j < 4; ++j)
    #pragma unroll
    for (int i = 0; i < 16; ++i) acc[j][i] = 1e30f;

  f32x16 zero = {};
  const unsigned char* abase = &afr[half][rq * 1024][0];

  #pragma unroll 4
  for (int step = 0; step < 16; ++step) {
    const unsigned char* a = abase + (size_t)step * (64 * 16) + (size_t)l31 * 16;
    short8 af0 = *(const short8*)(a);
    short8 af1 = *(const short8*)(a + 32 * 16);
    #pragma unroll
    for (int j = 0; j < 4; ++j) {
      f32x16 c0 = __builtin_amdgcn_mfma_f32_32x32x16_bf16(af0, bf[j], zero, 0, 0, 0);
      f32x16 c1 = __builtin_amdgcn_mfma_f32_32x32x16_bf16(af1, bf[j], zero, 0, 0, 0);
      #pragma unroll
      for (int i = 0; i < 16; ++i) acc[j][i] = m3(acc[j][i], c0[i], c1[i]);
    }
  }

  // ---- tail: fold rows, combine row-parity halves, cross-wave col min ----
  #pragma unroll
  for (int j = 0; j < 4; ++j) {
    float m = fold16(acc[j]);
    m = fminf(m, __shfl_xor(m, 32, 64));
    if (half == 0) cmin[w][j * 32 + l31] = m;
  }
  __syncthreads();

  float v = 0.f;
  if (tid < 256) {                 // col c: half ch owns waves ch, ch+2, ch+4, ch+6
    int ch = tid >> 7;
    int cc = tid & 127;
    float m0 = fminf(cmin[ch][cc], cmin[ch + 2][cc]);
    float m1 = fminf(cmin[ch + 4][cc], cmin[ch + 6][cc]);
    v = fmaxf(fminf(m0, m1), 0.0f);
  }
  // block sum (512 threads, threads >=256 contribute 0)
  #pragma unroll
  for (int off = 32; off > 0; off >>= 1)
    v += __shfl_down(v, off, 64);
  if (lane == 0) ssum[w] = v;
  __syncthreads();
  if (tid == 0) {
    float s = 0.f;
    #pragma unroll
    for (int q = 0; q < 8; ++q) s += ssum[q];
    atomicAdd(out, s * SCALE2);
  }
}

extern "C" void kernel_launch(void* const* d_in, const int* in_sizes, int n_in,
                              void* d_out, int out_size, void* d_ws, size_t ws_size,
                              hipStream_t stream) {
  const float* pred = (const float*)d_in[0];
  const float* tgt  = (const float*)d_in[1];
  float* out = (float*)d_out;
  (void)d_ws; (void)ws_size;

  hipMemsetAsync(out, 0, sizeof(float), stream);
  chamfer_fused_kernel<<<256, BLK, 0, stream>>>(pred, tgt, out);
}